// Round 5
// baseline (888.226 us; speedup 1.0000x reference)
//
#include <hip/hip_runtime.h>
#include <hip/hip_bf16.h>

#define N_NODE 100000
#define EMB 112
#define EMB2 56   // packed bf16x2 (uint) or float2 per row
#define NNZ 1000000
#define BATCH 512
#define SEQL 50
#define LAYERS 2

typedef unsigned int uint32;

// fp32 -> bf16 with round-to-nearest-even (no NaN in this data)
__device__ __forceinline__ unsigned short f2bf(float f) {
    uint32 u = __float_as_uint(f);
    u = (u + 0x7fffu + ((u >> 16) & 1u)) >> 16;
    return (unsigned short)u;
}
__device__ __forceinline__ uint32 pack_bf2(float x, float y) {
    return (uint32)f2bf(x) | ((uint32)f2bf(y) << 16);
}
__device__ __forceinline__ float2 unpack_bf2(uint32 p) {
    float2 r;
    r.x = __uint_as_float(p << 16);
    r.y = __uint_as_float(p & 0xffff0000u);
    return r;
}

#define NPAD 100352       // N_NODE rounded to 1024 multiple; = 196 * 512
#define NBUCKET 196       // 512 rows per bucket
#define BCAP 6144         // bucket edge capacity (Poisson mean 5120, 14 sigma)

// ---------------------------------------------------------------------------
// prep: (a) convert embedding fp32 -> packed bf16; (b) histogram of adj_rows
// into off; (c) session flags into flags and map.
// ---------------------------------------------------------------------------
__global__ void prep_kernel(const float2* __restrict__ embf2,
                            uint32* __restrict__ embb,
                            const int* __restrict__ rows, int* __restrict__ off,
                            const int* __restrict__ items,
                            int* __restrict__ flags, int* __restrict__ map) {
    int i = blockIdx.x * blockDim.x + threadIdx.x;
    if (i < N_NODE * EMB2) {
        float2 v = embf2[i];
        embb[i] = pack_bf2(v.x, v.y);
    }
    if (i < NNZ) atomicAdd(&off[rows[i]], 1);
    if (i < BATCH * SEQL) {
        int it = items[i];
        if (it > 0) { flags[it - 1] = 1; map[it - 1] = 1; }
    }
}

// ---------------------------------------------------------------------------
// Scan: in-place exclusive scan of [off | map] (2*NPAD elements), 1024/block.
// ---------------------------------------------------------------------------
#define SCAN_B 1024
__global__ void scan_block_kernel(int* __restrict__ a, int* __restrict__ bsum,
                                  int n) {
    __shared__ int s[256];
    int t = threadIdx.x;
    int base = blockIdx.x * SCAN_B + t * 4;
    int v0 = (base + 0 < n) ? a[base + 0] : 0;
    int v1 = (base + 1 < n) ? a[base + 1] : 0;
    int v2 = (base + 2 < n) ? a[base + 2] : 0;
    int v3 = (base + 3 < n) ? a[base + 3] : 0;
    int tsum = v0 + v1 + v2 + v3;
    s[t] = tsum;
    __syncthreads();
#pragma unroll
    for (int d = 1; d < 256; d <<= 1) {
        int x = (t >= d) ? s[t - d] : 0;
        __syncthreads();
        s[t] += x;
        __syncthreads();
    }
    int excl = s[t] - tsum;
    if (t == 255) bsum[blockIdx.x] = s[255];
    if (base + 0 < n) a[base + 0] = excl;
    if (base + 1 < n) a[base + 1] = excl + v0;
    if (base + 2 < n) a[base + 2] = excl + v0 + v1;
    if (base + 3 < n) a[base + 3] = excl + v0 + v1 + v2;
}

// Segmented exclusive scan of block sums: blocks [0,seg) and [seg,nb) restart.
__global__ void scan_sums_kernel(int* __restrict__ bsum, int nb, int seg) {
    __shared__ int s[256];
    int t = threadIdx.x;
    int v = (t < nb) ? bsum[t] : 0;
    s[t] = v;
    __syncthreads();
#pragma unroll
    for (int d = 1; d < 256; d <<= 1) {
        int x = (t >= d) ? s[t - d] : 0;
        __syncthreads();
        s[t] += x;
        __syncthreads();
    }
    int base = s[seg - 1];  // inclusive total of first segment
    if (t < nb) bsum[t] = (s[t] - v) - (t >= seg ? base : 0);
}

// += carry; also initializes the 196 bucket append-cursors (cur[b] = start of
// bucket b's contiguous CSR range = off[512b] after the add).
__global__ void scan_add_kernel(int* __restrict__ a, const int* __restrict__ bsum,
                                int n, int* __restrict__ cur) {
    int i = blockIdx.x * blockDim.x + threadIdx.x;
    if (i < n) {
        int v = a[i] + bsum[i >> 10];
        a[i] = v;
        if (i < NPAD && (i & 511) == 0) cur[i >> 9] = v;
    }
}

// ---------------------------------------------------------------------------
// Pass A: append edge to its bucket's region (196 moving frontiers).
// payload: (col | rowlocal<<17, val)  [col<2^17, rowlocal<512]
// ---------------------------------------------------------------------------
__global__ void bucket_scatter_kernel(const int* __restrict__ rows,
                                      const int* __restrict__ cols,
                                      const float* __restrict__ vals,
                                      int* __restrict__ cur,
                                      int2* __restrict__ tmp, int nnz) {
    int i = blockIdx.x * blockDim.x + threadIdx.x;
    if (i >= nnz) return;
    int r = rows[i];
    int p = atomicAdd(&cur[r >> 9], 1);
    tmp[p] = make_int2(cols[i] | ((r & 511) << 17), __float_as_int(vals[i]));
}

// ---------------------------------------------------------------------------
// Pass B: per-bucket LDS counting sort -> final (col,val) CSR, coalesced IO.
// One 256-thread block per bucket. Bucket b covers rows [512b, 512b+512),
// global range [off[512b], off[512b+512]) (contiguous).
// ---------------------------------------------------------------------------
__global__ __launch_bounds__(256)
void bucket_sort_kernel(const int* __restrict__ off,
                        const int2* __restrict__ tmp,
                        int2* __restrict__ edges) {
    __shared__ int lcur[512];
    __shared__ int2 stage[BCAP];
    int b = blockIdx.x;
    int t = threadIdx.x;
    int S = off[b << 9];
    int E = (b == NBUCKET - 1) ? NNZ : off[(b + 1) << 9];
    // init 512 local row cursors (relative to S)
    for (int j = t; j < 512; j += 256) {
        int gr = (b << 9) + j;
        lcur[j] = off[gr] - S;
    }
    __syncthreads();
    for (int i = S + t; i < E; i += 256) {
        int2 e = tmp[i];
        int rl = (e.x >> 17) & 511;
        int p = atomicAdd(&lcur[rl], 1);
        int2 o = make_int2(e.x & 0x1FFFF, e.y);
        if (p < BCAP) stage[p] = o;
        else edges[S + p] = o;  // never expected; safety
    }
    __syncthreads();
    int n = E - S;
    for (int i = t; i < n && i < BCAP; i += 256) edges[S + i] = stage[i];
}

// ---------------------------------------------------------------------------
// CSR gather SpMM over packed-bf16 rows; row per 64-lane wave.
// Lanes cooperatively prefetch up to 64 edge descriptors, then __shfl
// broadcast; k-loop's only memory ops are the (independent) row gathers.
// fuse_final: out_f32[map[r]] = (spmm + cur_bf16[r] + emb_f32[r]) / 3.
// else:       out_bf16[r] = spmm.
// ---------------------------------------------------------------------------
__global__ __launch_bounds__(256, 8)
void spmm_csr_kernel(const uint32* __restrict__ curb,
                     const float2* __restrict__ embf,
                     const int* __restrict__ rowptr,
                     const int2* __restrict__ edges,
                     const int* __restrict__ flags,
                     const int* __restrict__ map,
                     void* __restrict__ outm, int fuse_final) {
    int wid = threadIdx.x >> 6;
    int lane = threadIdx.x & 63;
    int r = (blockIdx.x << 2) + wid;
    if (r >= N_NODE) return;
    if (flags && !flags[r]) return;
    int beg = rowptr[r];
    int end = rowptr[r + 1];
    int len = end - beg;
    int lf = (lane < EMB2) ? lane : (EMB2 - 1);
    float2 acc = make_float2(0.0f, 0.0f);
    for (int base = 0; base < len; base += 64) {
        int m = len - base; if (m > 64) m = 64;
        int2 e = (lane < m) ? edges[beg + base + lane] : make_int2(0, 0);
        int k = 0;
        for (; k + 4 <= m; k += 4) {
            int c0 = __shfl(e.x, k + 0); float v0 = __int_as_float(__shfl(e.y, k + 0));
            int c1 = __shfl(e.x, k + 1); float v1 = __int_as_float(__shfl(e.y, k + 1));
            int c2 = __shfl(e.x, k + 2); float v2 = __int_as_float(__shfl(e.y, k + 2));
            int c3 = __shfl(e.x, k + 3); float v3 = __int_as_float(__shfl(e.y, k + 3));
            uint32 p0 = curb[c0 * EMB2 + lf];
            uint32 p1 = curb[c1 * EMB2 + lf];
            uint32 p2 = curb[c2 * EMB2 + lf];
            uint32 p3 = curb[c3 * EMB2 + lf];
            float2 x0 = unpack_bf2(p0), x1 = unpack_bf2(p1);
            float2 x2 = unpack_bf2(p2), x3 = unpack_bf2(p3);
            acc.x += v0 * x0.x; acc.y += v0 * x0.y;
            acc.x += v1 * x1.x; acc.y += v1 * x1.y;
            acc.x += v2 * x2.x; acc.y += v2 * x2.y;
            acc.x += v3 * x3.x; acc.y += v3 * x3.y;
        }
        for (; k < m; ++k) {
            int c = __shfl(e.x, k); float v = __int_as_float(__shfl(e.y, k));
            float2 x = unpack_bf2(curb[c * EMB2 + lf]);
            acc.x += v * x.x; acc.y += v * x.y;
        }
    }
    if (lane < EMB2) {
        if (fuse_final) {
            size_t o = (size_t)r * EMB2 + lane;
            float2 c = unpack_bf2(curb[o]);
            float2 eb = embf[o];
            acc.x = (acc.x + c.x + eb.x) * (1.0f / 3.0f);
            acc.y = (acc.y + c.y + eb.y) * (1.0f / 3.0f);
            ((float2*)outm)[(size_t)map[r] * EMB2 + lane] = acc;
        } else {
            ((uint32*)outm)[(size_t)r * EMB2 + lane] = pack_bf2(acc.x, acc.y);
        }
    }
}

// ---------------------------------------------------------------------------
// Pool over compacted fp32 item_emb.
// ---------------------------------------------------------------------------
__global__ void pool_kernel(const float* __restrict__ item_c,
                            const int* __restrict__ map,
                            const int* __restrict__ items,
                            const float* __restrict__ slen,
                            float* __restrict__ sess, float* __restrict__ acc) {
    int b = blockIdx.x;
    int f = threadIdx.x;
    if (f >= EMB) return;
    float s = 0.0f;
    for (int l = 0; l < SEQL; ++l) {
        int it = items[b * SEQL + l];
        if (it > 0) s += item_c[(size_t)map[it - 1] * EMB + f];
    }
    s /= slen[b];
    sess[b * EMB + f] = s;
    acc[b * EMB + f] = s;
}

// ---------------------------------------------------------------------------
// DA = D @ A, 512^3 fp32. 64x64 tile, 16x16 threads, 4x4 per thread, BK=16.
// ---------------------------------------------------------------------------
__global__ __launch_bounds__(256)
void gemm_da_kernel(const float* __restrict__ D, const float* __restrict__ A,
                    float* __restrict__ DA) {
    __shared__ float sDt[16][68];
    __shared__ float sA[16][68];
    int t = threadIdx.x;
    int tx = t & 15, ty = t >> 4;
    int m0 = blockIdx.y * 64, n0 = blockIdx.x * 64;
    float acc[4][4];
#pragma unroll
    for (int i = 0; i < 4; ++i)
#pragma unroll
        for (int j = 0; j < 4; ++j) acc[i][j] = 0.0f;

    int dm = t >> 2, dk = (t & 3) * 4;
    int ak = t >> 4, an = (t & 15) * 4;
    for (int k0 = 0; k0 < BATCH; k0 += 16) {
        float4 dv = *(const float4*)(D + (size_t)(m0 + dm) * BATCH + k0 + dk);
        float4 av = *(const float4*)(A + (size_t)(k0 + ak) * BATCH + n0 + an);
        __syncthreads();
        sDt[dk + 0][dm] = dv.x;
        sDt[dk + 1][dm] = dv.y;
        sDt[dk + 2][dm] = dv.z;
        sDt[dk + 3][dm] = dv.w;
        *(float4*)&sA[ak][an] = av;
        __syncthreads();
#pragma unroll
        for (int k = 0; k < 16; ++k) {
            float4 a = *(const float4*)&sDt[k][ty * 4];
            float4 b = *(const float4*)&sA[k][tx * 4];
            float ar[4] = {a.x, a.y, a.z, a.w};
            float br[4] = {b.x, b.y, b.z, b.w};
#pragma unroll
            for (int i = 0; i < 4; ++i)
#pragma unroll
                for (int j = 0; j < 4; ++j) acc[i][j] += ar[i] * br[j];
        }
    }
#pragma unroll
    for (int i = 0; i < 4; ++i) {
        float4 o = make_float4(acc[i][0], acc[i][1], acc[i][2], acc[i][3]);
        *(float4*)(DA + (size_t)(m0 + ty * 4 + i) * BATCH + n0 + tx * 4) = o;
    }
}

// ---------------------------------------------------------------------------
// t = sess @ W^T
// ---------------------------------------------------------------------------
__global__ void lin_kernel(const float* __restrict__ sess,
                           const float* __restrict__ W,
                           float* __restrict__ t) {
    __shared__ float srow[EMB];
    int b = blockIdx.x;
    int j = threadIdx.x;
    if (j < EMB) srow[j] = sess[b * EMB + j];
    __syncthreads();
    if (j >= EMB) return;
    float a = 0.0f;
#pragma unroll 4
    for (int k = 0; k < EMB; ++k) a += srow[k] * W[j * EMB + k];
    t[b * EMB + j] = a;
}

// ---------------------------------------------------------------------------
// s2 = l2norm_row(DA @ t); sess = s2; acc += s2; if final: out = acc / 3.
// ---------------------------------------------------------------------------
__global__ void damul_norm_kernel(const float* __restrict__ DA,
                                  const float* __restrict__ t,
                                  float* __restrict__ sess,
                                  float* __restrict__ acc,
                                  float* __restrict__ out, int final_layer) {
    int b = blockIdx.x;
    int j = threadIdx.x;  // 0..127
    float v = 0.0f;
    if (j < EMB) {
        const float* darow = DA + (size_t)b * BATCH;
        for (int k0 = 0; k0 < BATCH; k0 += 4) {
            float4 d4 = *(const float4*)(darow + k0);
            float t0 = t[(k0 + 0) * EMB + j];
            float t1 = t[(k0 + 1) * EMB + j];
            float t2 = t[(k0 + 2) * EMB + j];
            float t3 = t[(k0 + 3) * EMB + j];
            v += d4.x * t0 + d4.y * t1 + d4.z * t2 + d4.w * t3;
        }
    }
    float sq = (j < EMB) ? v * v : 0.0f;
#pragma unroll
    for (int off = 32; off > 0; off >>= 1) sq += __shfl_down(sq, off, 64);
    __shared__ float partial[2];
    if ((j & 63) == 0) partial[j >> 6] = sq;
    __syncthreads();
    float norm = sqrtf(partial[0] + partial[1]);
    float inv = 1.0f / fmaxf(norm, 1e-12f);
    if (j < EMB) {
        float s = v * inv;
        sess[b * EMB + j] = s;
        float a = acc[b * EMB + j] + s;
        acc[b * EMB + j] = a;
        if (final_layer) out[b * EMB + j] = a * (1.0f / 3.0f);
    }
}

extern "C" void kernel_launch(void* const* d_in, const int* in_sizes, int n_in,
                              void* d_out, int out_size, void* d_ws, size_t ws_size,
                              hipStream_t stream) {
    const float* embedding = (const float*)d_in[0];
    const float* adj_vals  = (const float*)d_in[1];
    const int*   adj_rows  = (const int*)d_in[2];
    const int*   adj_cols  = (const int*)d_in[3];
    const float* D         = (const float*)d_in[4];
    const float* A         = (const float*)d_in[5];
    const int*   sess_item = (const int*)d_in[6];
    const float* sess_len  = (const float*)d_in[7];
    const float* w_sess    = (const float*)d_in[8];
    float* out = (float*)d_out;

    // Workspace layout (128B-aligned offsets); total ~75.4 MB
    char* ws = (char*)d_ws;
    uint32* embb   = (uint32*)(ws);                 // 22,400,000 bf16 embedding
    uint32* next1b = (uint32*)(ws + 22400000);      // 22,400,000 bf16 S(emb)
    int2*   edges  = (int2*)(ws + 44800000);        //  8,000,000 final CSR
    int2*   etmp   = (int2*)(ws + 52800000);        //  8,000,000 bucket staging
    int*    off    = (int*)(ws + 60800000);         //    401,408 (NPAD ints)
    int*    mapv   = (int*)(ws + 61201408);         //    401,408
    int*    flags  = (int*)(ws + 61602816);         //    401,408
    int*    bsum   = (int*)(ws + 62004224);         //      1,024
    int*    curb   = (int*)(ws + 62005248);         //      1,024 (196 used)
    float*  item_c = (float*)(ws + 62006272);       // 11,468,800 (25600 rows)
    float*  DA     = (float*)(ws + 73475072);       //  1,048,576
    float*  sess   = (float*)(ws + 74523648);       //    229,376
    float*  tbuf   = (float*)(ws + 74753024);       //    229,376
    float*  accb   = (float*)(ws + 74982400);       //    229,376

    // zero off|map|flags in one shot (contiguous)
    hipMemsetAsync(off, 0, 3 * NPAD * sizeof(int), stream);

    // prep: bf16 convert + histogram + flags
    prep_kernel<<<(N_NODE * EMB2 + 255) / 256, 256, 0, stream>>>(
        (const float2*)embedding, embb, adj_rows, off, sess_item, flags, mapv);

    // fused exclusive scans of off (row starts) and map (compaction)
    {
        int n2 = 2 * NPAD;
        int nb2 = n2 / SCAN_B;  // 196
        scan_block_kernel<<<nb2, 256, 0, stream>>>(off, bsum, n2);
        scan_sums_kernel<<<1, 256, 0, stream>>>(bsum, nb2, NPAD / SCAN_B);
        scan_add_kernel<<<(n2 + 255) / 256, 256, 0, stream>>>(off, bsum, n2, curb);
    }

    // two-phase CSR build: bucket append then per-bucket LDS sort
    bucket_scatter_kernel<<<(NNZ + 255) / 256, 256, 0, stream>>>(
        adj_rows, adj_cols, adj_vals, curb, etmp, NNZ);
    bucket_sort_kernel<<<NBUCKET, 256, 0, stream>>>(off, etmp, edges);

    // hyperconv (bf16 gathers, fp32 accumulate)
    {
        int grid = (N_NODE + 3) / 4;
        spmm_csr_kernel<<<grid, 256, 0, stream>>>(embb, nullptr, off, edges,
                                                  nullptr, nullptr, next1b, 0);
        spmm_csr_kernel<<<grid, 256, 0, stream>>>(next1b, (const float2*)embedding,
                                                  off, edges, flags, mapv, item_c, 1);
    }

    // sessconv
    {
        dim3 grid(BATCH / 64, BATCH / 64);
        gemm_da_kernel<<<grid, 256, 0, stream>>>(D, A, DA);
    }
    pool_kernel<<<BATCH, 128, 0, stream>>>(item_c, mapv, sess_item, sess_len,
                                           sess, accb);
    for (int i = 0; i < LAYERS; ++i) {
        lin_kernel<<<BATCH, 128, 0, stream>>>(sess, w_sess + (size_t)i * EMB * EMB, tbuf);
        damul_norm_kernel<<<BATCH, 128, 0, stream>>>(DA, tbuf, sess, accb, out,
                                                     i == LAYERS - 1);
    }
}

// Round 6
// 357.083 us; speedup vs baseline: 2.4874x; 2.4874x over previous
//
#include <hip/hip_runtime.h>
#include <hip/hip_bf16.h>

#define N_NODE 100000
#define EMB 112
#define EMB2 56   // packed bf16x2 (uint) or float2 per row
#define NNZ 1000000
#define BATCH 512
#define SEQL 50
#define LAYERS 2

typedef unsigned int uint32;

// fp32 -> bf16 with round-to-nearest-even (no NaN in this data)
__device__ __forceinline__ unsigned short f2bf(float f) {
    uint32 u = __float_as_uint(f);
    u = (u + 0x7fffu + ((u >> 16) & 1u)) >> 16;
    return (unsigned short)u;
}
__device__ __forceinline__ uint32 pack_bf2(float x, float y) {
    return (uint32)f2bf(x) | ((uint32)f2bf(y) << 16);
}
__device__ __forceinline__ float2 unpack_bf2(uint32 p) {
    float2 r;
    r.x = __uint_as_float(p << 16);
    r.y = __uint_as_float(p & 0xffff0000u);
    return r;
}

#define NPAD 100352       // N_NODE rounded to 1024 multiple; = 196 * 512
#define NBUCKET 196       // 512 rows per bucket
#define BCAP 6144         // bucket edge capacity (Poisson mean 5120)
#define CHUNK 4096        // edges per multi-split block

// ---------------------------------------------------------------------------
// prep: (a) convert embedding fp32 -> packed bf16; (b) histogram of adj_rows
// into off (100K counters - low contention); (c) session flags.
// ---------------------------------------------------------------------------
__global__ void prep_kernel(const float2* __restrict__ embf2,
                            uint32* __restrict__ embb,
                            const int* __restrict__ rows, int* __restrict__ off,
                            const int* __restrict__ items,
                            int* __restrict__ flags, int* __restrict__ map) {
    int i = blockIdx.x * blockDim.x + threadIdx.x;
    if (i < N_NODE * EMB2) {
        float2 v = embf2[i];
        embb[i] = pack_bf2(v.x, v.y);
    }
    if (i < NNZ) atomicAdd(&off[rows[i]], 1);
    if (i < BATCH * SEQL) {
        int it = items[i];
        if (it > 0) { flags[it - 1] = 1; map[it - 1] = 1; }
    }
}

// ---------------------------------------------------------------------------
// Scan: in-place exclusive scan of [off | map] (2*NPAD elements), 1024/block.
// ---------------------------------------------------------------------------
#define SCAN_B 1024
__global__ void scan_block_kernel(int* __restrict__ a, int* __restrict__ bsum,
                                  int n) {
    __shared__ int s[256];
    int t = threadIdx.x;
    int base = blockIdx.x * SCAN_B + t * 4;
    int v0 = (base + 0 < n) ? a[base + 0] : 0;
    int v1 = (base + 1 < n) ? a[base + 1] : 0;
    int v2 = (base + 2 < n) ? a[base + 2] : 0;
    int v3 = (base + 3 < n) ? a[base + 3] : 0;
    int tsum = v0 + v1 + v2 + v3;
    s[t] = tsum;
    __syncthreads();
#pragma unroll
    for (int d = 1; d < 256; d <<= 1) {
        int x = (t >= d) ? s[t - d] : 0;
        __syncthreads();
        s[t] += x;
        __syncthreads();
    }
    int excl = s[t] - tsum;
    if (t == 255) bsum[blockIdx.x] = s[255];
    if (base + 0 < n) a[base + 0] = excl;
    if (base + 1 < n) a[base + 1] = excl + v0;
    if (base + 2 < n) a[base + 2] = excl + v0 + v1;
    if (base + 3 < n) a[base + 3] = excl + v0 + v1 + v2;
}

// Segmented exclusive scan of block sums: blocks [0,seg) and [seg,nb) restart.
__global__ void scan_sums_kernel(int* __restrict__ bsum, int nb, int seg) {
    __shared__ int s[256];
    int t = threadIdx.x;
    int v = (t < nb) ? bsum[t] : 0;
    s[t] = v;
    __syncthreads();
#pragma unroll
    for (int d = 1; d < 256; d <<= 1) {
        int x = (t >= d) ? s[t - d] : 0;
        __syncthreads();
        s[t] += x;
        __syncthreads();
    }
    int base = s[seg - 1];  // inclusive total of first segment
    if (t < nb) bsum[t] = (s[t] - v) - (t >= seg ? base : 0);
}

// += carry; also initializes the 196 bucket cursors (cur[b] = off[512b]).
__global__ void scan_add_kernel(int* __restrict__ a, const int* __restrict__ bsum,
                                int n, int* __restrict__ cur) {
    int i = blockIdx.x * blockDim.x + threadIdx.x;
    if (i < n) {
        int v = a[i] + bsum[i >> 10];
        a[i] = v;
        if (i < NPAD && (i & 511) == 0) cur[i >> 9] = v;
    }
}

// ---------------------------------------------------------------------------
// Pass A: block-aggregated multi-split into 196 bucket regions.
// Per block: LDS hist -> one global atomicAdd per (block,bucket) to reserve a
// contiguous range -> LDS-staged rank -> linear coalesced dump.
// payload: (col | rowlocal<<17, val)
// ---------------------------------------------------------------------------
__global__ __launch_bounds__(256)
void multi_split_kernel(const int* __restrict__ rows,
                        const int* __restrict__ cols,
                        const float* __restrict__ vals,
                        int* __restrict__ cur, int2* __restrict__ tmp, int nnz) {
    __shared__ int hist[NBUCKET];
    __shared__ int lexcl[NBUCKET];
    __shared__ int gbase[NBUCKET];
    __shared__ int lcur[NBUCKET];
    __shared__ int sscan[256];
    __shared__ unsigned char sbuck[CHUNK];
    __shared__ int2 stage[CHUNK];  // 32 KB
    int t = threadIdx.x;
    int base = blockIdx.x * CHUNK;
    int m = nnz - base; if (m > CHUNK) m = CHUNK;

    for (int j = t; j < NBUCKET; j += 256) hist[j] = 0;
    __syncthreads();
    for (int i = t; i < m; i += 256) atomicAdd(&hist[rows[base + i] >> 9], 1);
    __syncthreads();
    // exclusive scan of 196 counts (padded to 256)
    int v = (t < NBUCKET) ? hist[t] : 0;
    sscan[t] = v;
    __syncthreads();
#pragma unroll
    for (int d = 1; d < 256; d <<= 1) {
        int x = (t >= d) ? sscan[t - d] : 0;
        __syncthreads();
        sscan[t] += x;
        __syncthreads();
    }
    if (t < NBUCKET) {
        int e = sscan[t] - v;
        lexcl[t] = e;
        lcur[t] = e;
        gbase[t] = atomicAdd(&cur[t], v);  // reserve contiguous range
    }
    __syncthreads();
    // rank + stage (sorted by bucket inside LDS)
    for (int i = t; i < m; i += 256) {
        int r = rows[base + i];
        int b = r >> 9;
        int p = atomicAdd(&lcur[b], 1);
        stage[p] = make_int2(cols[base + i] | ((r & 511) << 17),
                             __float_as_int(vals[base + i]));
        sbuck[p] = (unsigned char)b;
    }
    __syncthreads();
    // linear dump: consecutive staged entries -> consecutive global addresses
    for (int i = t; i < m; i += 256) {
        int b = sbuck[i];
        tmp[gbase[b] + (i - lexcl[b])] = stage[i];
    }
}

// ---------------------------------------------------------------------------
// Pass B: per-bucket LDS counting sort -> final (col,val) CSR, coalesced IO.
// ---------------------------------------------------------------------------
__global__ __launch_bounds__(256)
void bucket_sort_kernel(const int* __restrict__ off,
                        const int2* __restrict__ tmp,
                        int2* __restrict__ edges) {
    __shared__ int lcur[512];
    __shared__ int2 stage[BCAP];
    int b = blockIdx.x;
    int t = threadIdx.x;
    int S = off[b << 9];
    int E = (b == NBUCKET - 1) ? NNZ : off[(b + 1) << 9];
    for (int j = t; j < 512; j += 256) lcur[j] = off[(b << 9) + j] - S;
    __syncthreads();
    for (int i = S + t; i < E; i += 256) {
        int2 e = tmp[i];
        int rl = (e.x >> 17) & 511;
        int p = atomicAdd(&lcur[rl], 1);
        int2 o = make_int2(e.x & 0x1FFFF, e.y);
        if (p < BCAP) stage[p] = o;
        else edges[S + p] = o;  // overflow safety; not expected
    }
    __syncthreads();
    int n = E - S;
    for (int i = t; i < n && i < BCAP; i += 256) edges[S + i] = stage[i];
}

// ---------------------------------------------------------------------------
// CSR gather SpMM over packed-bf16 rows; row per 64-lane wave.
// ---------------------------------------------------------------------------
__global__ __launch_bounds__(256, 8)
void spmm_csr_kernel(const uint32* __restrict__ curb,
                     const float2* __restrict__ embf,
                     const int* __restrict__ rowptr,
                     const int2* __restrict__ edges,
                     const int* __restrict__ flags,
                     const int* __restrict__ map,
                     void* __restrict__ outm, int fuse_final) {
    int wid = threadIdx.x >> 6;
    int lane = threadIdx.x & 63;
    int r = (blockIdx.x << 2) + wid;
    if (r >= N_NODE) return;
    if (flags && !flags[r]) return;
    int beg = rowptr[r];
    int end = rowptr[r + 1];
    int len = end - beg;
    int lf = (lane < EMB2) ? lane : (EMB2 - 1);
    float2 acc = make_float2(0.0f, 0.0f);
    for (int base = 0; base < len; base += 64) {
        int m = len - base; if (m > 64) m = 64;
        int2 e = (lane < m) ? edges[beg + base + lane] : make_int2(0, 0);
        int k = 0;
        for (; k + 4 <= m; k += 4) {
            int c0 = __shfl(e.x, k + 0); float v0 = __int_as_float(__shfl(e.y, k + 0));
            int c1 = __shfl(e.x, k + 1); float v1 = __int_as_float(__shfl(e.y, k + 1));
            int c2 = __shfl(e.x, k + 2); float v2 = __int_as_float(__shfl(e.y, k + 2));
            int c3 = __shfl(e.x, k + 3); float v3 = __int_as_float(__shfl(e.y, k + 3));
            uint32 p0 = curb[c0 * EMB2 + lf];
            uint32 p1 = curb[c1 * EMB2 + lf];
            uint32 p2 = curb[c2 * EMB2 + lf];
            uint32 p3 = curb[c3 * EMB2 + lf];
            float2 x0 = unpack_bf2(p0), x1 = unpack_bf2(p1);
            float2 x2 = unpack_bf2(p2), x3 = unpack_bf2(p3);
            acc.x += v0 * x0.x; acc.y += v0 * x0.y;
            acc.x += v1 * x1.x; acc.y += v1 * x1.y;
            acc.x += v2 * x2.x; acc.y += v2 * x2.y;
            acc.x += v3 * x3.x; acc.y += v3 * x3.y;
        }
        for (; k < m; ++k) {
            int c = __shfl(e.x, k); float v = __int_as_float(__shfl(e.y, k));
            float2 x = unpack_bf2(curb[c * EMB2 + lf]);
            acc.x += v * x.x; acc.y += v * x.y;
        }
    }
    if (lane < EMB2) {
        if (fuse_final) {
            size_t o = (size_t)r * EMB2 + lane;
            float2 c = unpack_bf2(curb[o]);
            float2 eb = embf[o];
            acc.x = (acc.x + c.x + eb.x) * (1.0f / 3.0f);
            acc.y = (acc.y + c.y + eb.y) * (1.0f / 3.0f);
            ((float2*)outm)[(size_t)map[r] * EMB2 + lane] = acc;
        } else {
            ((uint32*)outm)[(size_t)r * EMB2 + lane] = pack_bf2(acc.x, acc.y);
        }
    }
}

// ---------------------------------------------------------------------------
// Pool over compacted fp32 item_emb.
// ---------------------------------------------------------------------------
__global__ void pool_kernel(const float* __restrict__ item_c,
                            const int* __restrict__ map,
                            const int* __restrict__ items,
                            const float* __restrict__ slen,
                            float* __restrict__ sess, float* __restrict__ acc) {
    int b = blockIdx.x;
    int f = threadIdx.x;
    if (f >= EMB) return;
    float s = 0.0f;
    for (int l = 0; l < SEQL; ++l) {
        int it = items[b * SEQL + l];
        if (it > 0) s += item_c[(size_t)map[it - 1] * EMB + f];
    }
    s /= slen[b];
    sess[b * EMB + f] = s;
    acc[b * EMB + f] = s;
}

// ---------------------------------------------------------------------------
// DA = D @ A, 512^3 fp32. 64x64 tile, 16x16 threads, 4x4 per thread, BK=16.
// ---------------------------------------------------------------------------
__global__ __launch_bounds__(256)
void gemm_da_kernel(const float* __restrict__ D, const float* __restrict__ A,
                    float* __restrict__ DA) {
    __shared__ float sDt[16][68];
    __shared__ float sA[16][68];
    int t = threadIdx.x;
    int tx = t & 15, ty = t >> 4;
    int m0 = blockIdx.y * 64, n0 = blockIdx.x * 64;
    float acc[4][4];
#pragma unroll
    for (int i = 0; i < 4; ++i)
#pragma unroll
        for (int j = 0; j < 4; ++j) acc[i][j] = 0.0f;

    int dm = t >> 2, dk = (t & 3) * 4;
    int ak = t >> 4, an = (t & 15) * 4;
    for (int k0 = 0; k0 < BATCH; k0 += 16) {
        float4 dv = *(const float4*)(D + (size_t)(m0 + dm) * BATCH + k0 + dk);
        float4 av = *(const float4*)(A + (size_t)(k0 + ak) * BATCH + n0 + an);
        __syncthreads();
        sDt[dk + 0][dm] = dv.x;
        sDt[dk + 1][dm] = dv.y;
        sDt[dk + 2][dm] = dv.z;
        sDt[dk + 3][dm] = dv.w;
        *(float4*)&sA[ak][an] = av;
        __syncthreads();
#pragma unroll
        for (int k = 0; k < 16; ++k) {
            float4 a = *(const float4*)&sDt[k][ty * 4];
            float4 b = *(const float4*)&sA[k][tx * 4];
            float ar[4] = {a.x, a.y, a.z, a.w};
            float br[4] = {b.x, b.y, b.z, b.w};
#pragma unroll
            for (int i = 0; i < 4; ++i)
#pragma unroll
                for (int j = 0; j < 4; ++j) acc[i][j] += ar[i] * br[j];
        }
    }
#pragma unroll
    for (int i = 0; i < 4; ++i) {
        float4 o = make_float4(acc[i][0], acc[i][1], acc[i][2], acc[i][3]);
        *(float4*)(DA + (size_t)(m0 + ty * 4 + i) * BATCH + n0 + tx * 4) = o;
    }
}

// ---------------------------------------------------------------------------
// t = sess @ W^T
// ---------------------------------------------------------------------------
__global__ void lin_kernel(const float* __restrict__ sess,
                           const float* __restrict__ W,
                           float* __restrict__ t) {
    __shared__ float srow[EMB];
    int b = blockIdx.x;
    int j = threadIdx.x;
    if (j < EMB) srow[j] = sess[b * EMB + j];
    __syncthreads();
    if (j >= EMB) return;
    float a = 0.0f;
#pragma unroll 4
    for (int k = 0; k < EMB; ++k) a += srow[k] * W[j * EMB + k];
    t[b * EMB + j] = a;
}

// ---------------------------------------------------------------------------
// s2 = l2norm_row(DA @ t); sess = s2; acc += s2; if final: out = acc / 3.
// ---------------------------------------------------------------------------
__global__ void damul_norm_kernel(const float* __restrict__ DA,
                                  const float* __restrict__ t,
                                  float* __restrict__ sess,
                                  float* __restrict__ acc,
                                  float* __restrict__ out, int final_layer) {
    int b = blockIdx.x;
    int j = threadIdx.x;  // 0..127
    float v = 0.0f;
    if (j < EMB) {
        const float* darow = DA + (size_t)b * BATCH;
        for (int k0 = 0; k0 < BATCH; k0 += 4) {
            float4 d4 = *(const float4*)(darow + k0);
            float t0 = t[(k0 + 0) * EMB + j];
            float t1 = t[(k0 + 1) * EMB + j];
            float t2 = t[(k0 + 2) * EMB + j];
            float t3 = t[(k0 + 3) * EMB + j];
            v += d4.x * t0 + d4.y * t1 + d4.z * t2 + d4.w * t3;
        }
    }
    float sq = (j < EMB) ? v * v : 0.0f;
#pragma unroll
    for (int off = 32; off > 0; off >>= 1) sq += __shfl_down(sq, off, 64);
    __shared__ float partial[2];
    if ((j & 63) == 0) partial[j >> 6] = sq;
    __syncthreads();
    float norm = sqrtf(partial[0] + partial[1]);
    float inv = 1.0f / fmaxf(norm, 1e-12f);
    if (j < EMB) {
        float s = v * inv;
        sess[b * EMB + j] = s;
        float a = acc[b * EMB + j] + s;
        acc[b * EMB + j] = a;
        if (final_layer) out[b * EMB + j] = a * (1.0f / 3.0f);
    }
}

extern "C" void kernel_launch(void* const* d_in, const int* in_sizes, int n_in,
                              void* d_out, int out_size, void* d_ws, size_t ws_size,
                              hipStream_t stream) {
    const float* embedding = (const float*)d_in[0];
    const float* adj_vals  = (const float*)d_in[1];
    const int*   adj_rows  = (const int*)d_in[2];
    const int*   adj_cols  = (const int*)d_in[3];
    const float* D         = (const float*)d_in[4];
    const float* A         = (const float*)d_in[5];
    const int*   sess_item = (const int*)d_in[6];
    const float* sess_len  = (const float*)d_in[7];
    const float* w_sess    = (const float*)d_in[8];
    float* out = (float*)d_out;

    // Workspace layout (128B-aligned offsets); total ~75.4 MB
    char* ws = (char*)d_ws;
    uint32* embb   = (uint32*)(ws);                 // 22,400,000 bf16 embedding
    uint32* next1b = (uint32*)(ws + 22400000);      // 22,400,000 bf16 S(emb)
    int2*   edges  = (int2*)(ws + 44800000);        //  8,000,000 final CSR
    int2*   etmp   = (int2*)(ws + 52800000);        //  8,000,000 bucket staging
    int*    off    = (int*)(ws + 60800000);         //    401,408 (NPAD ints)
    int*    mapv   = (int*)(ws + 61201408);         //    401,408
    int*    flags  = (int*)(ws + 61602816);         //    401,408
    int*    bsum   = (int*)(ws + 62004224);         //      1,024
    int*    curb   = (int*)(ws + 62005248);         //      1,024 (196 used)
    float*  item_c = (float*)(ws + 62006272);       // 11,468,800 (25600 rows)
    float*  DA     = (float*)(ws + 73475072);       //  1,048,576
    float*  sess   = (float*)(ws + 74523648);       //    229,376
    float*  tbuf   = (float*)(ws + 74753024);       //    229,376
    float*  accb   = (float*)(ws + 74982400);       //    229,376

    // zero off|map|flags in one shot (contiguous)
    hipMemsetAsync(off, 0, 3 * NPAD * sizeof(int), stream);

    // prep: bf16 convert + histogram + flags
    prep_kernel<<<(N_NODE * EMB2 + 255) / 256, 256, 0, stream>>>(
        (const float2*)embedding, embb, adj_rows, off, sess_item, flags, mapv);

    // fused exclusive scans of off (row starts) and map (compaction)
    {
        int n2 = 2 * NPAD;
        int nb2 = n2 / SCAN_B;  // 196
        scan_block_kernel<<<nb2, 256, 0, stream>>>(off, bsum, n2);
        scan_sums_kernel<<<1, 256, 0, stream>>>(bsum, nb2, NPAD / SCAN_B);
        scan_add_kernel<<<(n2 + 255) / 256, 256, 0, stream>>>(off, bsum, n2, curb);
    }

    // two-phase CSR build: block-aggregated multi-split, then per-bucket sort
    multi_split_kernel<<<(NNZ + CHUNK - 1) / CHUNK, 256, 0, stream>>>(
        adj_rows, adj_cols, adj_vals, curb, etmp, NNZ);
    bucket_sort_kernel<<<NBUCKET, 256, 0, stream>>>(off, etmp, edges);

    // hyperconv (bf16 gathers, fp32 accumulate)
    {
        int grid = (N_NODE + 3) / 4;
        spmm_csr_kernel<<<grid, 256, 0, stream>>>(embb, nullptr, off, edges,
                                                  nullptr, nullptr, next1b, 0);
        spmm_csr_kernel<<<grid, 256, 0, stream>>>(next1b, (const float2*)embedding,
                                                  off, edges, flags, mapv, item_c, 1);
    }

    // sessconv
    {
        dim3 grid(BATCH / 64, BATCH / 64);
        gemm_da_kernel<<<grid, 256, 0, stream>>>(D, A, DA);
    }
    pool_kernel<<<BATCH, 128, 0, stream>>>(item_c, mapv, sess_item, sess_len,
                                           sess, accb);
    for (int i = 0; i < LAYERS; ++i) {
        lin_kernel<<<BATCH, 128, 0, stream>>>(sess, w_sess + (size_t)i * EMB * EMB, tbuf);
        damul_norm_kernel<<<BATCH, 128, 0, stream>>>(DA, tbuf, sess, accb, out,
                                                     i == LAYERS - 1);
    }
}

// Round 7
// 320.546 us; speedup vs baseline: 2.7710x; 1.1140x over previous
//
#include <hip/hip_runtime.h>
#include <hip/hip_bf16.h>

#define N_NODE 100000
#define EMB 112
#define EMB2 56   // packed bf16x2 (uint) or float2 per row
#define NNZ 1000000
#define BATCH 512
#define SEQL 50
#define LAYERS 2

typedef unsigned int uint32;

// fp32 -> bf16 with round-to-nearest-even (no NaN in this data)
__device__ __forceinline__ unsigned short f2bf(float f) {
    uint32 u = __float_as_uint(f);
    u = (u + 0x7fffu + ((u >> 16) & 1u)) >> 16;
    return (unsigned short)u;
}
__device__ __forceinline__ uint32 pack_bf2(float x, float y) {
    return (uint32)f2bf(x) | ((uint32)f2bf(y) << 16);
}
__device__ __forceinline__ float2 unpack_bf2(uint32 p) {
    float2 r;
    r.x = __uint_as_float(p << 16);
    r.y = __uint_as_float(p & 0xffff0000u);
    return r;
}

#define NPAD 100352       // 196 * 512
#define NBUCKET 196       // 512 rows per bucket
#define BCAP 6144         // bucket capacity: mean 5120, sd ~71 -> 14 sigma
#define CHUNK 4096        // edges per multi-split block

// ---------------------------------------------------------------------------
// prep: bf16 convert (streaming) + session flags + bucket cursor init.
// No global histogram atomics anymore.
// ---------------------------------------------------------------------------
__global__ void prep_kernel(const float2* __restrict__ embf2,
                            uint32* __restrict__ embb,
                            const int* __restrict__ items,
                            int* __restrict__ flags, int* __restrict__ map,
                            int* __restrict__ cur) {
    int i = blockIdx.x * blockDim.x + threadIdx.x;
    if (i < N_NODE * EMB2) {
        float2 v = embf2[i];
        embb[i] = pack_bf2(v.x, v.y);
    }
    if (i < BATCH * SEQL) {
        int it = items[i];
        if (it > 0) { flags[it - 1] = 1; map[it - 1] = 1; }
    }
    if (i < NBUCKET) cur[i] = i * BCAP;
}

// ---------------------------------------------------------------------------
// Exclusive scan (for map compaction), 1024 elems/block.
// ---------------------------------------------------------------------------
#define SCAN_B 1024
__global__ void scan_block_kernel(int* __restrict__ a, int* __restrict__ bsum,
                                  int n) {
    __shared__ int s[256];
    int t = threadIdx.x;
    int base = blockIdx.x * SCAN_B + t * 4;
    int v0 = (base + 0 < n) ? a[base + 0] : 0;
    int v1 = (base + 1 < n) ? a[base + 1] : 0;
    int v2 = (base + 2 < n) ? a[base + 2] : 0;
    int v3 = (base + 3 < n) ? a[base + 3] : 0;
    int tsum = v0 + v1 + v2 + v3;
    s[t] = tsum;
    __syncthreads();
#pragma unroll
    for (int d = 1; d < 256; d <<= 1) {
        int x = (t >= d) ? s[t - d] : 0;
        __syncthreads();
        s[t] += x;
        __syncthreads();
    }
    int excl = s[t] - tsum;
    if (t == 255) bsum[blockIdx.x] = s[255];
    if (base + 0 < n) a[base + 0] = excl;
    if (base + 1 < n) a[base + 1] = excl + v0;
    if (base + 2 < n) a[base + 2] = excl + v0 + v1;
    if (base + 3 < n) a[base + 3] = excl + v0 + v1 + v2;
}

__global__ void scan_sums_kernel(int* __restrict__ bsum, int nb) {
    __shared__ int s[256];
    int t = threadIdx.x;
    int v = (t < nb) ? bsum[t] : 0;
    s[t] = v;
    __syncthreads();
#pragma unroll
    for (int d = 1; d < 256; d <<= 1) {
        int x = (t >= d) ? s[t - d] : 0;
        __syncthreads();
        s[t] += x;
        __syncthreads();
    }
    if (t < nb) bsum[t] = s[t] - v;  // exclusive
}

__global__ void scan_add_kernel(int* __restrict__ a, const int* __restrict__ bsum,
                                int n) {
    int i = blockIdx.x * blockDim.x + threadIdx.x;
    if (i < n) a[i] += bsum[i >> 10];
}

// ---------------------------------------------------------------------------
// Pass A: block-aggregated multi-split into fixed-capacity bucket regions.
// payload: (col | rowlocal<<17, val)
// ---------------------------------------------------------------------------
__global__ __launch_bounds__(256)
void multi_split_kernel(const int* __restrict__ rows,
                        const int* __restrict__ cols,
                        const float* __restrict__ vals,
                        int* __restrict__ cur, int2* __restrict__ tmp, int nnz) {
    __shared__ int hist[NBUCKET];
    __shared__ int lexcl[NBUCKET];
    __shared__ int gbase[NBUCKET];
    __shared__ int lcur[NBUCKET];
    __shared__ int sscan[256];
    __shared__ unsigned char sbuck[CHUNK];
    __shared__ int2 stage[CHUNK];  // 32 KB
    int t = threadIdx.x;
    int base = blockIdx.x * CHUNK;
    int m = nnz - base; if (m > CHUNK) m = CHUNK;

    for (int j = t; j < NBUCKET; j += 256) hist[j] = 0;
    __syncthreads();
    for (int i = t; i < m; i += 256) atomicAdd(&hist[rows[base + i] >> 9], 1);
    __syncthreads();
    int v = (t < NBUCKET) ? hist[t] : 0;
    sscan[t] = v;
    __syncthreads();
#pragma unroll
    for (int d = 1; d < 256; d <<= 1) {
        int x = (t >= d) ? sscan[t - d] : 0;
        __syncthreads();
        sscan[t] += x;
        __syncthreads();
    }
    if (t < NBUCKET) {
        int e = sscan[t] - v;
        lexcl[t] = e;
        lcur[t] = e;
        gbase[t] = atomicAdd(&cur[t], v);  // reserve contiguous range
    }
    __syncthreads();
    for (int i = t; i < m; i += 256) {
        int r = rows[base + i];
        int b = r >> 9;
        int p = atomicAdd(&lcur[b], 1);
        stage[p] = make_int2(cols[base + i] | ((r & 511) << 17),
                             __float_as_int(vals[base + i]));
        sbuck[p] = (unsigned char)b;
    }
    __syncthreads();
    for (int i = t; i < m; i += 256) {
        int b = sbuck[i];
        tmp[gbase[b] + (i - lexcl[b])] = stage[i];
    }
}

// ---------------------------------------------------------------------------
// Pass B: per-bucket counting sort + CSR row-offset computation.
// Bucket b region: [b*BCAP, b*BCAP + cnt) in both tmp and edges.
// Writes off[512b + rl] = b*BCAP + rowstart(rl) for all 512 rl (coalesced).
// ---------------------------------------------------------------------------
__global__ __launch_bounds__(256)
void bucket_sort_kernel(const int* __restrict__ cur,
                        const int2* __restrict__ tmp,
                        int2* __restrict__ edges, int* __restrict__ off) {
    __shared__ int hist[512];
    __shared__ int scanb[512];
    __shared__ int lcur[512];
    __shared__ int sscan[256];
    __shared__ int2 stage[BCAP];  // 48 KB
    int b = blockIdx.x;
    int t = threadIdx.x;
    int base = b * BCAP;
    int cnt = cur[b] - base;
    for (int j = t; j < 512; j += 256) hist[j] = 0;
    __syncthreads();
    for (int i = t; i < cnt; i += 256)
        atomicAdd(&hist[(tmp[base + i].x >> 17) & 511], 1);
    __syncthreads();
    // exclusive scan of 512 counts with 256 threads (pairwise)
    int a0 = hist[2 * t], a1 = hist[2 * t + 1];
    int s = a0 + a1;
    sscan[t] = s;
    __syncthreads();
#pragma unroll
    for (int d = 1; d < 256; d <<= 1) {
        int x = (t >= d) ? sscan[t - d] : 0;
        __syncthreads();
        sscan[t] += x;
        __syncthreads();
    }
    int excl = sscan[t] - s;
    scanb[2 * t] = excl;
    scanb[2 * t + 1] = excl + a0;
    lcur[2 * t] = excl;
    lcur[2 * t + 1] = excl + a0;
    __syncthreads();
    for (int j = t; j < 512; j += 256) off[(b << 9) + j] = base + scanb[j];
    for (int i = t; i < cnt; i += 256) {
        int2 e = tmp[base + i];
        int rl = (e.x >> 17) & 511;
        int p = atomicAdd(&lcur[rl], 1);
        stage[p] = make_int2(e.x & 0x1FFFF, e.y);
    }
    __syncthreads();
    for (int i = t; i < cnt; i += 256) edges[base + i] = stage[i];
}

// ---------------------------------------------------------------------------
// CSR gather SpMM over packed-bf16 rows; row per 64-lane wave.
// Row end: next row's start, except at bucket boundary -> bucket end (bend).
// ---------------------------------------------------------------------------
__global__ __launch_bounds__(256, 8)
void spmm_csr_kernel(const uint32* __restrict__ curb,
                     const float2* __restrict__ embf,
                     const int* __restrict__ rowptr,
                     const int* __restrict__ bend,
                     const int2* __restrict__ edges,
                     const int* __restrict__ flags,
                     const int* __restrict__ map,
                     void* __restrict__ outm, int fuse_final) {
    int wid = threadIdx.x >> 6;
    int lane = threadIdx.x & 63;
    int r = (blockIdx.x << 2) + wid;
    if (r >= N_NODE) return;
    if (flags && !flags[r]) return;
    int beg = rowptr[r];
    int end = ((r & 511) == 511) ? bend[r >> 9] : rowptr[r + 1];
    int len = end - beg;
    int lf = (lane < EMB2) ? lane : (EMB2 - 1);
    float2 acc = make_float2(0.0f, 0.0f);
    for (int base = 0; base < len; base += 64) {
        int m = len - base; if (m > 64) m = 64;
        int2 e = (lane < m) ? edges[beg + base + lane] : make_int2(0, 0);
        int k = 0;
        for (; k + 4 <= m; k += 4) {
            int c0 = __shfl(e.x, k + 0); float v0 = __int_as_float(__shfl(e.y, k + 0));
            int c1 = __shfl(e.x, k + 1); float v1 = __int_as_float(__shfl(e.y, k + 1));
            int c2 = __shfl(e.x, k + 2); float v2 = __int_as_float(__shfl(e.y, k + 2));
            int c3 = __shfl(e.x, k + 3); float v3 = __int_as_float(__shfl(e.y, k + 3));
            uint32 p0 = curb[c0 * EMB2 + lf];
            uint32 p1 = curb[c1 * EMB2 + lf];
            uint32 p2 = curb[c2 * EMB2 + lf];
            uint32 p3 = curb[c3 * EMB2 + lf];
            float2 x0 = unpack_bf2(p0), x1 = unpack_bf2(p1);
            float2 x2 = unpack_bf2(p2), x3 = unpack_bf2(p3);
            acc.x += v0 * x0.x; acc.y += v0 * x0.y;
            acc.x += v1 * x1.x; acc.y += v1 * x1.y;
            acc.x += v2 * x2.x; acc.y += v2 * x2.y;
            acc.x += v3 * x3.x; acc.y += v3 * x3.y;
        }
        for (; k < m; ++k) {
            int c = __shfl(e.x, k); float v = __int_as_float(__shfl(e.y, k));
            float2 x = unpack_bf2(curb[c * EMB2 + lf]);
            acc.x += v * x.x; acc.y += v * x.y;
        }
    }
    if (lane < EMB2) {
        if (fuse_final) {
            size_t o = (size_t)r * EMB2 + lane;
            float2 c = unpack_bf2(curb[o]);
            float2 eb = embf[o];
            acc.x = (acc.x + c.x + eb.x) * (1.0f / 3.0f);
            acc.y = (acc.y + c.y + eb.y) * (1.0f / 3.0f);
            ((float2*)outm)[(size_t)map[r] * EMB2 + lane] = acc;
        } else {
            ((uint32*)outm)[(size_t)r * EMB2 + lane] = pack_bf2(acc.x, acc.y);
        }
    }
}

// ---------------------------------------------------------------------------
// Pool over compacted fp32 item_emb.
// ---------------------------------------------------------------------------
__global__ void pool_kernel(const float* __restrict__ item_c,
                            const int* __restrict__ map,
                            const int* __restrict__ items,
                            const float* __restrict__ slen,
                            float* __restrict__ sess, float* __restrict__ acc) {
    int b = blockIdx.x;
    int f = threadIdx.x;
    if (f >= EMB) return;
    float s = 0.0f;
    for (int l = 0; l < SEQL; ++l) {
        int it = items[b * SEQL + l];
        if (it > 0) s += item_c[(size_t)map[it - 1] * EMB + f];
    }
    s /= slen[b];
    sess[b * EMB + f] = s;
    acc[b * EMB + f] = s;
}

// ---------------------------------------------------------------------------
// DA = D @ A, 512^3 fp32. 64x64 tile, 4x4 per thread, BK=16.
// ---------------------------------------------------------------------------
__global__ __launch_bounds__(256)
void gemm_da_kernel(const float* __restrict__ D, const float* __restrict__ A,
                    float* __restrict__ DA) {
    __shared__ float sDt[16][68];
    __shared__ float sA[16][68];
    int t = threadIdx.x;
    int tx = t & 15, ty = t >> 4;
    int m0 = blockIdx.y * 64, n0 = blockIdx.x * 64;
    float acc[4][4];
#pragma unroll
    for (int i = 0; i < 4; ++i)
#pragma unroll
        for (int j = 0; j < 4; ++j) acc[i][j] = 0.0f;

    int dm = t >> 2, dk = (t & 3) * 4;
    int ak = t >> 4, an = (t & 15) * 4;
    for (int k0 = 0; k0 < BATCH; k0 += 16) {
        float4 dv = *(const float4*)(D + (size_t)(m0 + dm) * BATCH + k0 + dk);
        float4 av = *(const float4*)(A + (size_t)(k0 + ak) * BATCH + n0 + an);
        __syncthreads();
        sDt[dk + 0][dm] = dv.x;
        sDt[dk + 1][dm] = dv.y;
        sDt[dk + 2][dm] = dv.z;
        sDt[dk + 3][dm] = dv.w;
        *(float4*)&sA[ak][an] = av;
        __syncthreads();
#pragma unroll
        for (int k = 0; k < 16; ++k) {
            float4 a = *(const float4*)&sDt[k][ty * 4];
            float4 b = *(const float4*)&sA[k][tx * 4];
            float ar[4] = {a.x, a.y, a.z, a.w};
            float br[4] = {b.x, b.y, b.z, b.w};
#pragma unroll
            for (int i = 0; i < 4; ++i)
#pragma unroll
                for (int j = 0; j < 4; ++j) acc[i][j] += ar[i] * br[j];
        }
    }
#pragma unroll
    for (int i = 0; i < 4; ++i) {
        float4 o = make_float4(acc[i][0], acc[i][1], acc[i][2], acc[i][3]);
        *(float4*)(DA + (size_t)(m0 + ty * 4 + i) * BATCH + n0 + tx * 4) = o;
    }
}

// ---------------------------------------------------------------------------
// t = sess @ W^T
// ---------------------------------------------------------------------------
__global__ void lin_kernel(const float* __restrict__ sess,
                           const float* __restrict__ W,
                           float* __restrict__ t) {
    __shared__ float srow[EMB];
    int b = blockIdx.x;
    int j = threadIdx.x;
    if (j < EMB) srow[j] = sess[b * EMB + j];
    __syncthreads();
    if (j >= EMB) return;
    float a = 0.0f;
#pragma unroll 4
    for (int k = 0; k < EMB; ++k) a += srow[k] * W[j * EMB + k];
    t[b * EMB + j] = a;
}

// ---------------------------------------------------------------------------
// s2 = l2norm_row(DA @ t); sess = s2; acc += s2; if final: out = acc / 3.
// ---------------------------------------------------------------------------
__global__ void damul_norm_kernel(const float* __restrict__ DA,
                                  const float* __restrict__ t,
                                  float* __restrict__ sess,
                                  float* __restrict__ acc,
                                  float* __restrict__ out, int final_layer) {
    int b = blockIdx.x;
    int j = threadIdx.x;  // 0..127
    float v = 0.0f;
    if (j < EMB) {
        const float* darow = DA + (size_t)b * BATCH;
        for (int k0 = 0; k0 < BATCH; k0 += 4) {
            float4 d4 = *(const float4*)(darow + k0);
            float t0 = t[(k0 + 0) * EMB + j];
            float t1 = t[(k0 + 1) * EMB + j];
            float t2 = t[(k0 + 2) * EMB + j];
            float t3 = t[(k0 + 3) * EMB + j];
            v += d4.x * t0 + d4.y * t1 + d4.z * t2 + d4.w * t3;
        }
    }
    float sq = (j < EMB) ? v * v : 0.0f;
#pragma unroll
    for (int off = 32; off > 0; off >>= 1) sq += __shfl_down(sq, off, 64);
    __shared__ float partial[2];
    if ((j & 63) == 0) partial[j >> 6] = sq;
    __syncthreads();
    float norm = sqrtf(partial[0] + partial[1]);
    float inv = 1.0f / fmaxf(norm, 1e-12f);
    if (j < EMB) {
        float s = v * inv;
        sess[b * EMB + j] = s;
        float a = acc[b * EMB + j] + s;
        acc[b * EMB + j] = a;
        if (final_layer) out[b * EMB + j] = a * (1.0f / 3.0f);
    }
}

extern "C" void kernel_launch(void* const* d_in, const int* in_sizes, int n_in,
                              void* d_out, int out_size, void* d_ws, size_t ws_size,
                              hipStream_t stream) {
    const float* embedding = (const float*)d_in[0];
    const float* adj_vals  = (const float*)d_in[1];
    const int*   adj_rows  = (const int*)d_in[2];
    const int*   adj_cols  = (const int*)d_in[3];
    const float* D         = (const float*)d_in[4];
    const float* A         = (const float*)d_in[5];
    const int*   sess_item = (const int*)d_in[6];
    const float* sess_len  = (const float*)d_in[7];
    const float* w_sess    = (const float*)d_in[8];
    float* out = (float*)d_out;

    // Workspace layout (128B-aligned); total ~68.9 MB
    char* ws = (char*)d_ws;
    uint32* embb   = (uint32*)(ws);                 // 22,400,000 bf16 embedding
    uint32* next1b = (uint32*)(ws + 22400000);      // 22,400,000 bf16 S(emb)
    int2*   edges  = (int2*)(ws + 44800000);        //  9,633,792 (196*6144*8)
    int*    off    = (int*)(ws + 54433792);         //    401,408 (NPAD)
    int*    mapv   = (int*)(ws + 54835200);         //    401,408
    int*    flags  = (int*)(ws + 55236608);         //    401,408
    int*    bsum   = (int*)(ws + 55638016);         //      1,024
    int*    curb   = (int*)(ws + 55639040);         //      1,024 (196 used)
    float*  item_c = (float*)(ws + 55640064);       // 11,468,800 (25600 rows)
    int2*   etmp   = (int2*)(ws + 55640064);        //  9,633,792 ALIAS: dead
                                                    //  before item_c is written
    float*  DA     = (float*)(ws + 67108864);       //  1,048,576
    float*  sess   = (float*)(ws + 68157440);       //    229,376
    float*  tbuf   = (float*)(ws + 68386816);       //    229,376
    float*  accb   = (float*)(ws + 68616192);       //    229,376

    // zero map|flags (contiguous)
    hipMemsetAsync(mapv, 0, 2 * NPAD * sizeof(int), stream);

    // prep: bf16 convert + flags + bucket cursor init (no histogram)
    prep_kernel<<<(N_NODE * EMB2 + 255) / 256, 256, 0, stream>>>(
        (const float2*)embedding, embb, sess_item, flags, mapv, curb);

    // map compaction scan (NPAD)
    {
        int nb = NPAD / SCAN_B;  // 98
        scan_block_kernel<<<nb, 256, 0, stream>>>(mapv, bsum, NPAD);
        scan_sums_kernel<<<1, 256, 0, stream>>>(bsum, nb);
        scan_add_kernel<<<(NPAD + 255) / 256, 256, 0, stream>>>(mapv, bsum, NPAD);
    }

    // CSR build: multi-split into fixed bucket regions, then per-bucket sort
    multi_split_kernel<<<(NNZ + CHUNK - 1) / CHUNK, 256, 0, stream>>>(
        adj_rows, adj_cols, adj_vals, curb, etmp, NNZ);
    bucket_sort_kernel<<<NBUCKET, 256, 0, stream>>>(curb, etmp, edges, off);

    // hyperconv (bf16 gathers, fp32 accumulate)
    {
        int grid = (N_NODE + 3) / 4;
        spmm_csr_kernel<<<grid, 256, 0, stream>>>(embb, nullptr, off, curb, edges,
                                                  nullptr, nullptr, next1b, 0);
        spmm_csr_kernel<<<grid, 256, 0, stream>>>(next1b, (const float2*)embedding,
                                                  off, curb, edges, flags, mapv,
                                                  item_c, 1);
    }

    // sessconv
    {
        dim3 grid(BATCH / 64, BATCH / 64);
        gemm_da_kernel<<<grid, 256, 0, stream>>>(D, A, DA);
    }
    pool_kernel<<<BATCH, 128, 0, stream>>>(item_c, mapv, sess_item, sess_len,
                                           sess, accb);
    for (int i = 0; i < LAYERS; ++i) {
        lin_kernel<<<BATCH, 128, 0, stream>>>(sess, w_sess + (size_t)i * EMB * EMB, tbuf);
        damul_norm_kernel<<<BATCH, 128, 0, stream>>>(DA, tbuf, sess, accb, out,
                                                     i == LAYERS - 1);
    }
}

// Round 8
// 295.064 us; speedup vs baseline: 3.0103x; 1.0864x over previous
//
#include <hip/hip_runtime.h>
#include <hip/hip_bf16.h>

#define N_NODE 100000
#define EMB 112
#define EMB2 56   // bf16 pairs per row
#define EMBQ 28   // uint2 (4 bf16) per row
#define NNZ 1000000
#define BATCH 512
#define SEQL 50
#define LAYERS 2

typedef unsigned int uint32;

// fp32 -> bf16 round-to-nearest-even (no NaN in this data)
__device__ __forceinline__ unsigned short f2bf(float f) {
    uint32 u = __float_as_uint(f);
    u = (u + 0x7fffu + ((u >> 16) & 1u)) >> 16;
    return (unsigned short)u;
}
__device__ __forceinline__ uint32 pack_bf2(float x, float y) {
    return (uint32)f2bf(x) | ((uint32)f2bf(y) << 16);
}
__device__ __forceinline__ float2 unpack_bf2(uint32 p) {
    float2 r;
    r.x = __uint_as_float(p << 16);
    r.y = __uint_as_float(p & 0xffff0000u);
    return r;
}

#define NPAD 100352       // 196 * 512
#define NBUCKET 196       // 512 rows per bucket
#define BCAP 6144         // bucket capacity (mean 5102, ~14 sigma headroom)
#define CHUNK 4096        // edges per multi-split block

// ---------------------------------------------------------------------------
// prep: bf16 convert (vectorized, streaming) + session flags (=1; poison !=1
// elsewhere, so no memset needed) + bucket cursor init.
// ---------------------------------------------------------------------------
__global__ void prep_kernel(const float4* __restrict__ embf4,
                            uint2* __restrict__ embb2,
                            const int* __restrict__ items,
                            int* __restrict__ flags, int* __restrict__ cur) {
    int i = blockIdx.x * blockDim.x + threadIdx.x;
    if (i < N_NODE * EMBQ) {
        float4 v = embf4[i];
        uint2 o;
        o.x = pack_bf2(v.x, v.y);
        o.y = pack_bf2(v.z, v.w);
        embb2[i] = o;
    }
    if (i < BATCH * SEQL) {
        int it = items[i];
        if (it > 0) flags[it - 1] = 1;
    }
    if (i < NBUCKET) cur[i] = i * BCAP;
}

// ---------------------------------------------------------------------------
// Exclusive scan of indicator (flags[i]==1) -> mapv. 1024 elems/block.
// ---------------------------------------------------------------------------
#define SCAN_B 1024
__global__ void scan_block_kernel(const int* __restrict__ in,
                                  int* __restrict__ outa,
                                  int* __restrict__ bsum, int n) {
    __shared__ int s[256];
    int t = threadIdx.x;
    int base = blockIdx.x * SCAN_B + t * 4;
    int v0 = (base + 0 < n && in[base + 0] == 1) ? 1 : 0;
    int v1 = (base + 1 < n && in[base + 1] == 1) ? 1 : 0;
    int v2 = (base + 2 < n && in[base + 2] == 1) ? 1 : 0;
    int v3 = (base + 3 < n && in[base + 3] == 1) ? 1 : 0;
    int tsum = v0 + v1 + v2 + v3;
    s[t] = tsum;
    __syncthreads();
#pragma unroll
    for (int d = 1; d < 256; d <<= 1) {
        int x = (t >= d) ? s[t - d] : 0;
        __syncthreads();
        s[t] += x;
        __syncthreads();
    }
    int excl = s[t] - tsum;
    if (t == 255) bsum[blockIdx.x] = s[255];
    if (base + 0 < n) outa[base + 0] = excl;
    if (base + 1 < n) outa[base + 1] = excl + v0;
    if (base + 2 < n) outa[base + 2] = excl + v0 + v1;
    if (base + 3 < n) outa[base + 3] = excl + v0 + v1 + v2;
}

__global__ void scan_sums_kernel(int* __restrict__ bsum, int nb) {
    __shared__ int s[256];
    int t = threadIdx.x;
    int v = (t < nb) ? bsum[t] : 0;
    s[t] = v;
    __syncthreads();
#pragma unroll
    for (int d = 1; d < 256; d <<= 1) {
        int x = (t >= d) ? s[t - d] : 0;
        __syncthreads();
        s[t] += x;
        __syncthreads();
    }
    if (t < nb) bsum[t] = s[t] - v;  // exclusive
}

__global__ void scan_add_kernel(int* __restrict__ a, const int* __restrict__ bsum,
                                int n) {
    int i = blockIdx.x * blockDim.x + threadIdx.x;
    if (i < n) a[i] += bsum[i >> 10];
}

// ---------------------------------------------------------------------------
// Pass A: block-aggregated multi-split into fixed-capacity bucket regions.
// payload: (col | rowlocal<<17, val)
// ---------------------------------------------------------------------------
__global__ __launch_bounds__(256)
void multi_split_kernel(const int* __restrict__ rows,
                        const int* __restrict__ cols,
                        const float* __restrict__ vals,
                        int* __restrict__ cur, int2* __restrict__ tmp, int nnz) {
    __shared__ int hist[NBUCKET];
    __shared__ int lexcl[NBUCKET];
    __shared__ int gbase[NBUCKET];
    __shared__ int lcur[NBUCKET];
    __shared__ int sscan[256];
    __shared__ unsigned char sbuck[CHUNK];
    __shared__ int2 stage[CHUNK];  // 32 KB
    int t = threadIdx.x;
    int base = blockIdx.x * CHUNK;
    int m = nnz - base; if (m > CHUNK) m = CHUNK;

    for (int j = t; j < NBUCKET; j += 256) hist[j] = 0;
    __syncthreads();
    for (int i = t; i < m; i += 256) atomicAdd(&hist[rows[base + i] >> 9], 1);
    __syncthreads();
    int v = (t < NBUCKET) ? hist[t] : 0;
    sscan[t] = v;
    __syncthreads();
#pragma unroll
    for (int d = 1; d < 256; d <<= 1) {
        int x = (t >= d) ? sscan[t - d] : 0;
        __syncthreads();
        sscan[t] += x;
        __syncthreads();
    }
    if (t < NBUCKET) {
        int e = sscan[t] - v;
        lexcl[t] = e;
        lcur[t] = e;
        gbase[t] = atomicAdd(&cur[t], v);  // reserve contiguous range
    }
    __syncthreads();
    for (int i = t; i < m; i += 256) {
        int r = rows[base + i];
        int b = r >> 9;
        int p = atomicAdd(&lcur[b], 1);
        stage[p] = make_int2(cols[base + i] | ((r & 511) << 17),
                             __float_as_int(vals[base + i]));
        sbuck[p] = (unsigned char)b;
    }
    __syncthreads();
    for (int i = t; i < m; i += 256) {
        int b = sbuck[i];
        tmp[gbase[b] + (i - lexcl[b])] = stage[i];
    }
}

// ---------------------------------------------------------------------------
// Pass B: per-bucket counting sort + CSR row-offset computation.
// ---------------------------------------------------------------------------
__global__ __launch_bounds__(256)
void bucket_sort_kernel(const int* __restrict__ cur,
                        const int2* __restrict__ tmp,
                        int2* __restrict__ edges, int* __restrict__ off) {
    __shared__ int hist[512];
    __shared__ int scanb[512];
    __shared__ int lcur[512];
    __shared__ int sscan[256];
    __shared__ int2 stage[BCAP];  // 48 KB
    int b = blockIdx.x;
    int t = threadIdx.x;
    int base = b * BCAP;
    int cnt = cur[b] - base;
    for (int j = t; j < 512; j += 256) hist[j] = 0;
    __syncthreads();
    for (int i = t; i < cnt; i += 256)
        atomicAdd(&hist[(tmp[base + i].x >> 17) & 511], 1);
    __syncthreads();
    int a0 = hist[2 * t], a1 = hist[2 * t + 1];
    int s = a0 + a1;
    sscan[t] = s;
    __syncthreads();
#pragma unroll
    for (int d = 1; d < 256; d <<= 1) {
        int x = (t >= d) ? sscan[t - d] : 0;
        __syncthreads();
        sscan[t] += x;
        __syncthreads();
    }
    int excl = sscan[t] - s;
    scanb[2 * t] = excl;
    scanb[2 * t + 1] = excl + a0;
    lcur[2 * t] = excl;
    lcur[2 * t + 1] = excl + a0;
    __syncthreads();
    for (int j = t; j < 512; j += 256) off[(b << 9) + j] = base + scanb[j];
    for (int i = t; i < cnt; i += 256) {
        int2 e = tmp[base + i];
        int rl = (e.x >> 17) & 511;
        int p = atomicAdd(&lcur[rl], 1);
        stage[p] = make_int2(e.x & 0x1FFFF, e.y);
    }
    __syncthreads();
    for (int i = t; i < cnt; i += 256) edges[base + i] = stage[i];
}

// ---------------------------------------------------------------------------
// CSR gather SpMM, paired-edge layout: parity = lane>>5 picks edge k+parity;
// q = lane&31 (<28) gathers uint2 (4 bf16 features). One 8B/lane load covers
// TWO edge rows per step; parity partials merge via shfl_down(32).
// Lanes >= m prefetch (col=0,val=0) so no remainder loop is needed.
// ---------------------------------------------------------------------------
__global__ __launch_bounds__(256, 8)
void spmm_csr_kernel(const uint32* __restrict__ curb,
                     const float4* __restrict__ embf,
                     const int* __restrict__ rowptr,
                     const int* __restrict__ bend,
                     const int2* __restrict__ edges,
                     const int* __restrict__ flags,
                     const int* __restrict__ map,
                     void* __restrict__ outm, int fuse_final) {
    int wid = threadIdx.x >> 6;
    int lane = threadIdx.x & 63;
    int r = (blockIdx.x << 2) + wid;
    if (r >= N_NODE) return;
    if (flags && flags[r] != 1) return;
    int beg = rowptr[r];
    int end = ((r & 511) == 511) ? bend[r >> 9] : rowptr[r + 1];
    int len = end - beg;
    int q = lane & 31; if (q > EMBQ - 1) q = EMBQ - 1;
    int pidx = lane >> 5;
    const uint2* base = (const uint2*)curb;
    float4 acc = make_float4(0.0f, 0.0f, 0.0f, 0.0f);
    for (int b0 = 0; b0 < len; b0 += 64) {
        int m = len - b0; if (m > 64) m = 64;
        int2 e = (lane < m) ? edges[beg + b0 + lane] : make_int2(0, 0);
        for (int k = 0; k < m; k += 4) {
            int s0 = k + pidx, s1 = k + 2 + pidx;
            int   c0 = __shfl(e.x, s0);
            float v0 = __int_as_float(__shfl(e.y, s0));
            int   c1 = __shfl(e.x, s1);
            float v1 = __int_as_float(__shfl(e.y, s1));
            uint2 x0 = base[c0 * EMBQ + q];
            uint2 x1 = base[c1 * EMBQ + q];
            float2 p00 = unpack_bf2(x0.x), p01 = unpack_bf2(x0.y);
            float2 p10 = unpack_bf2(x1.x), p11 = unpack_bf2(x1.y);
            acc.x += v0 * p00.x; acc.y += v0 * p00.y;
            acc.z += v0 * p01.x; acc.w += v0 * p01.y;
            acc.x += v1 * p10.x; acc.y += v1 * p10.y;
            acc.z += v1 * p11.x; acc.w += v1 * p11.y;
        }
    }
    acc.x += __shfl_down(acc.x, 32);
    acc.y += __shfl_down(acc.y, 32);
    acc.z += __shfl_down(acc.z, 32);
    acc.w += __shfl_down(acc.w, 32);
    if (lane < EMBQ) {
        int o = r * EMBQ + lane;
        if (fuse_final) {
            uint2 cb = ((const uint2*)curb)[o];
            float2 c0f = unpack_bf2(cb.x), c1f = unpack_bf2(cb.y);
            float4 eb = embf[o];
            float4 res;
            res.x = (acc.x + c0f.x + eb.x) * (1.0f / 3.0f);
            res.y = (acc.y + c0f.y + eb.y) * (1.0f / 3.0f);
            res.z = (acc.z + c1f.x + eb.z) * (1.0f / 3.0f);
            res.w = (acc.w + c1f.y + eb.w) * (1.0f / 3.0f);
            ((float4*)outm)[(size_t)map[r] * EMBQ + lane] = res;
        } else {
            uint2 o2;
            o2.x = pack_bf2(acc.x, acc.y);
            o2.y = pack_bf2(acc.z, acc.w);
            ((uint2*)outm)[o] = o2;
        }
    }
}

// ---------------------------------------------------------------------------
// Fused: blocks 0..63 compute DA = D@A (64x64 tile, 4x4/thread);
// blocks 64..319 pool 2 sessions each from compacted item_c.
// ---------------------------------------------------------------------------
__global__ __launch_bounds__(256)
void gemm_pool_kernel(const float* __restrict__ D, const float* __restrict__ A,
                      float* __restrict__ DA,
                      const float* __restrict__ item_c,
                      const int* __restrict__ map,
                      const int* __restrict__ items,
                      const float* __restrict__ slen,
                      float* __restrict__ sess, float* __restrict__ accb) {
    __shared__ float sDt[16][68];
    __shared__ float sA[16][68];
    int t = threadIdx.x;
    if (blockIdx.x < 64) {
        int tx = t & 15, ty = t >> 4;
        int m0 = (blockIdx.x >> 3) * 64, n0 = (blockIdx.x & 7) * 64;
        float acc[4][4];
#pragma unroll
        for (int i = 0; i < 4; ++i)
#pragma unroll
            for (int j = 0; j < 4; ++j) acc[i][j] = 0.0f;
        int dm = t >> 2, dk = (t & 3) * 4;
        int ak = t >> 4, an = (t & 15) * 4;
        for (int k0 = 0; k0 < BATCH; k0 += 16) {
            float4 dv = *(const float4*)(D + (size_t)(m0 + dm) * BATCH + k0 + dk);
            float4 av = *(const float4*)(A + (size_t)(k0 + ak) * BATCH + n0 + an);
            __syncthreads();
            sDt[dk + 0][dm] = dv.x;
            sDt[dk + 1][dm] = dv.y;
            sDt[dk + 2][dm] = dv.z;
            sDt[dk + 3][dm] = dv.w;
            *(float4*)&sA[ak][an] = av;
            __syncthreads();
#pragma unroll
            for (int k = 0; k < 16; ++k) {
                float4 a = *(const float4*)&sDt[k][ty * 4];
                float4 b = *(const float4*)&sA[k][tx * 4];
                float ar[4] = {a.x, a.y, a.z, a.w};
                float br[4] = {b.x, b.y, b.z, b.w};
#pragma unroll
                for (int i = 0; i < 4; ++i)
#pragma unroll
                    for (int j = 0; j < 4; ++j) acc[i][j] += ar[i] * br[j];
            }
        }
#pragma unroll
        for (int i = 0; i < 4; ++i) {
            float4 o = make_float4(acc[i][0], acc[i][1], acc[i][2], acc[i][3]);
            *(float4*)(DA + (size_t)(m0 + ty * 4 + i) * BATCH + n0 + tx * 4) = o;
        }
    } else {
        int b = ((blockIdx.x - 64) << 1) + (t >> 7);  // session index
        int f = t & 127;
        if (f >= EMB) return;
        float s = 0.0f;
        for (int l = 0; l < SEQL; ++l) {
            int it = items[b * SEQL + l];
            if (it > 0) s += item_c[(size_t)map[it - 1] * EMB + f];
        }
        s /= slen[b];
        sess[b * EMB + f] = s;
        accb[b * EMB + f] = s;
    }
}

// ---------------------------------------------------------------------------
// t = sess @ W^T
// ---------------------------------------------------------------------------
__global__ void lin_kernel(const float* __restrict__ sess,
                           const float* __restrict__ W,
                           float* __restrict__ t) {
    __shared__ float srow[EMB];
    int b = blockIdx.x;
    int j = threadIdx.x;
    if (j < EMB) srow[j] = sess[b * EMB + j];
    __syncthreads();
    if (j >= EMB) return;
    float a = 0.0f;
#pragma unroll 4
    for (int k = 0; k < EMB; ++k) a += srow[k] * W[j * EMB + k];
    t[b * EMB + j] = a;
}

// ---------------------------------------------------------------------------
// s2 = l2norm_row(DA @ t); sess = s2; acc += s2; if final: out = acc / 3.
// ---------------------------------------------------------------------------
__global__ void damul_norm_kernel(const float* __restrict__ DA,
                                  const float* __restrict__ t,
                                  float* __restrict__ sess,
                                  float* __restrict__ acc,
                                  float* __restrict__ out, int final_layer) {
    int b = blockIdx.x;
    int j = threadIdx.x;  // 0..127
    float v = 0.0f;
    if (j < EMB) {
        const float* darow = DA + (size_t)b * BATCH;
        for (int k0 = 0; k0 < BATCH; k0 += 4) {
            float4 d4 = *(const float4*)(darow + k0);
            float t0 = t[(k0 + 0) * EMB + j];
            float t1 = t[(k0 + 1) * EMB + j];
            float t2 = t[(k0 + 2) * EMB + j];
            float t3 = t[(k0 + 3) * EMB + j];
            v += d4.x * t0 + d4.y * t1 + d4.z * t2 + d4.w * t3;
        }
    }
    float sq = (j < EMB) ? v * v : 0.0f;
#pragma unroll
    for (int off = 32; off > 0; off >>= 1) sq += __shfl_down(sq, off, 64);
    __shared__ float partial[2];
    if ((j & 63) == 0) partial[j >> 6] = sq;
    __syncthreads();
    float norm = sqrtf(partial[0] + partial[1]);
    float inv = 1.0f / fmaxf(norm, 1e-12f);
    if (j < EMB) {
        float s = v * inv;
        sess[b * EMB + j] = s;
        float a = acc[b * EMB + j] + s;
        acc[b * EMB + j] = a;
        if (final_layer) out[b * EMB + j] = a * (1.0f / 3.0f);
    }
}

extern "C" void kernel_launch(void* const* d_in, const int* in_sizes, int n_in,
                              void* d_out, int out_size, void* d_ws, size_t ws_size,
                              hipStream_t stream) {
    const float* embedding = (const float*)d_in[0];
    const float* adj_vals  = (const float*)d_in[1];
    const int*   adj_rows  = (const int*)d_in[2];
    const int*   adj_cols  = (const int*)d_in[3];
    const float* D         = (const float*)d_in[4];
    const float* A         = (const float*)d_in[5];
    const int*   sess_item = (const int*)d_in[6];
    const float* sess_len  = (const float*)d_in[7];
    const float* w_sess    = (const float*)d_in[8];
    float* out = (float*)d_out;

    // Workspace layout (128B-aligned); total ~68.9 MB
    char* ws = (char*)d_ws;
    uint32* embb   = (uint32*)(ws);                 // 22,400,000 bf16 embedding
    uint32* next1b = (uint32*)(ws + 22400000);      // 22,400,000 bf16 S(emb)
    int2*   edges  = (int2*)(ws + 44800000);        //  9,633,792 (196*6144*8)
    int*    off    = (int*)(ws + 54433792);         //    401,408 (NPAD)
    int*    mapv   = (int*)(ws + 54835200);         //    401,408
    int*    flags  = (int*)(ws + 55236608);         //    401,408
    int*    bsum   = (int*)(ws + 55638016);         //      1,024
    int*    curb   = (int*)(ws + 55639040);         //      1,024 (196 used)
    float*  item_c = (float*)(ws + 55640064);       // 11,468,800 (25600 rows)
    int2*   etmp   = (int2*)(ws + 55640064);        //  9,633,792 ALIAS: dead
                                                    //  before item_c is written
    float*  DA     = (float*)(ws + 67108864);       //  1,048,576
    float*  sess   = (float*)(ws + 68157440);       //    229,376
    float*  tbuf   = (float*)(ws + 68386816);       //    229,376
    float*  accb   = (float*)(ws + 68616192);       //    229,376

    // prep: bf16 convert + flags(=1; poison elsewhere) + cursor init. No memset.
    prep_kernel<<<(N_NODE * EMBQ + 255) / 256, 256, 0, stream>>>(
        (const float4*)embedding, (uint2*)embb, sess_item, flags, curb);

    // map compaction scan: mapv = exclusive_scan(flags == 1)
    {
        int nb = NPAD / SCAN_B;  // 98
        scan_block_kernel<<<nb, 256, 0, stream>>>(flags, mapv, bsum, NPAD);
        scan_sums_kernel<<<1, 256, 0, stream>>>(bsum, nb);
        scan_add_kernel<<<(NPAD + 255) / 256, 256, 0, stream>>>(mapv, bsum, NPAD);
    }

    // CSR build: multi-split into fixed bucket regions, then per-bucket sort
    multi_split_kernel<<<(NNZ + CHUNK - 1) / CHUNK, 256, 0, stream>>>(
        adj_rows, adj_cols, adj_vals, curb, etmp, NNZ);
    bucket_sort_kernel<<<NBUCKET, 256, 0, stream>>>(curb, etmp, edges, off);

    // hyperconv (paired-edge bf16 gathers, fp32 accumulate)
    {
        int grid = (N_NODE + 3) / 4;
        spmm_csr_kernel<<<grid, 256, 0, stream>>>(embb, nullptr, off, curb, edges,
                                                  nullptr, nullptr, next1b, 0);
        spmm_csr_kernel<<<grid, 256, 0, stream>>>(next1b, (const float4*)embedding,
                                                  off, curb, edges, flags, mapv,
                                                  item_c, 1);
    }

    // sessconv: fused DA=D@A + pooling, then 2 layers
    gemm_pool_kernel<<<320, 256, 0, stream>>>(D, A, DA, item_c, mapv, sess_item,
                                              sess_len, sess, accb);
    for (int i = 0; i < LAYERS; ++i) {
        lin_kernel<<<BATCH, 128, 0, stream>>>(sess, w_sess + (size_t)i * EMB * EMB, tbuf);
        damul_norm_kernel<<<BATCH, 128, 0, stream>>>(DA, tbuf, sess, accb, out,
                                                     i == LAYERS - 1);
    }
}